// Round 16
// baseline (66.067 us; speedup 1.0000x reference)
//
#include <hip/hip_runtime.h>
#include <math.h>

#define Nn 8192
#define Dd 256
#define NBINS 64
#define NSPLIT 8

typedef __attribute__((ext_vector_type(8))) short short8;
typedef __attribute__((ext_vector_type(4))) float f32x4;

#define GLOAD16(g, l)                                                        \
  __builtin_amdgcn_global_load_lds(                                          \
      (const __attribute__((address_space(1))) void*)(g),                    \
      (__attribute__((address_space(3))) void*)(l), 16, 0, 0)

static __device__ __forceinline__ unsigned short f2bf(float f) {
  unsigned int u = __float_as_uint(f);
  u = (u + 0x7fffu + ((u >> 16) & 1u)) >> 16;  // RNE
  return (unsigned short)u;
}
// order-preserving bijection float -> uint (atomicMax/Min on uint handles negatives)
static __device__ __forceinline__ unsigned int enc_ord(float f) {
  unsigned int u = __float_as_uint(f);
  return (u & 0x80000000u) ? ~u : (u | 0x80000000u);
}
static __device__ __forceinline__ float dec_ord(unsigned int u) {
  unsigned int b2 = (u & 0x80000000u) ? (u ^ 0x80000000u) : ~u;
  return __uint_as_float(b2);
}

// ---------------- K0: bf16 cast + fused (norm,label) + init accumulators ----------------
__global__ __launch_bounds__(256) void prep_kernel(const float* __restrict__ x,
                                                   const int* __restrict__ lab,
                                                   unsigned short* __restrict__ xb,
                                                   float2* __restrict__ sqlab,
                                                   unsigned int* __restrict__ pos2,
                                                   unsigned int* __restrict__ neg2,
                                                   unsigned int* __restrict__ gmm,
                                                   float* __restrict__ ghist,
                                                   float* __restrict__ ghsum,
                                                   unsigned int* __restrict__ cnt) {
  const int w = threadIdx.x >> 6;
  const int lane = threadIdx.x & 63;
  const int row = blockIdx.x * 4 + w;
  const float4 v = *(const float4*)(x + (size_t)row * Dd + lane * 4);
  ushort4 b;
  b.x = f2bf(v.x); b.y = f2bf(v.y); b.z = f2bf(v.z); b.w = f2bf(v.w);
  *(ushort4*)(xb + (size_t)row * Dd + lane * 4) = b;
  float s = v.x * v.x + v.y * v.y + v.z * v.z + v.w * v.w;
#pragma unroll
  for (int off = 32; off >= 1; off >>= 1) s += __shfl_xor(s, off);
  if (lane == 0) {
    sqlab[row] = make_float2(s, __int_as_float(lab[row]));
    pos2[row] = 0x007fffffu;  // enc_ord(-inf)
    neg2[row] = 0xff800000u;  // enc_ord(+inf)
  }
  if (blockIdx.x == 0 && threadIdx.x < NBINS) {
    ghist[threadIdx.x] = 0.0f;
    ghsum[threadIdx.x] = 0.0f;
    if (threadIdx.x == 0) { gmm[0] = 0x007fffffu; gmm[1] = 0xff800000u; cnt[0] = 0u; }
  }
}

// stage one A half-K tile (128 rows x 128 k = 32KB), XOR chunk placement, 512 threads
static __device__ __forceinline__ void stage_a(const unsigned short* __restrict__ xb,
                                               int r0, int hh, unsigned short* buf, int t) {
#pragma unroll
  for (int i = 0; i < 4; ++i) {
    const int c = i * 512 + t;          // 0..2047
    const int col = c >> 4;             // 0..127
    const int kq = (c & 15) ^ (col & 15);
    GLOAD16(xb + (size_t)(r0 + col) * Dd + hh * 128 + kq * 8, buf + (size_t)c * 8);
  }
}
// stage one B half-K tile (64 cols x 128 k = 16KB), 2 global_load_lds per thread
static __device__ __forceinline__ void stage_b(const unsigned short* __restrict__ xb,
                                               int c0, int hh, unsigned short* buf, int t) {
#pragma unroll
  for (int i = 0; i < 2; ++i) {
    const int c = i * 512 + t;          // 0..1023
    const int col = c >> 4;             // 0..63
    const int kq = (c & 15) ^ (col & 15);
    GLOAD16(xb + (size_t)(c0 + col) * Dd + hh * 128 + kq * 8, buf + (size_t)c * 8);
  }
}

// ---------------- K1: MFMA Gram + fused masked max/min (32x32 wave tiles, 4 waves/SIMD) ----------------
// 512-thread blocks: 8 waves in a 4x2 grid, wave tile 32 rows x 32 cols, block tile 128x64,
// 16 ct per 1024-col split. Per-wave registers ~124 (af[16]=64 + acc 16 + pmax/nmin 16 +
// labp 4 + temps) -> __launch_bounds__(512,4) forces the <=128 band: 2 blocks/CU x 2
// waves/SIMD/block = 4 waves/SIMD, doubling latency hiding vs the 2-wave family (r5-r15).
// Schedule = r15: 1 barrier/tile, full-tile double-buffer with static ping-pong, B frags
// at point of use (no live-across-MFMA prefetch regs), max3-form epilogue.
__global__ __launch_bounds__(512, 4) void pairwise_kernel(const unsigned short* __restrict__ xb,
                                                          const float2* __restrict__ sqlab,
                                                          unsigned int* __restrict__ pos2,
                                                          unsigned int* __restrict__ neg2) {
  __shared__ __align__(16) unsigned short Us[4096 * 8];  // 64KB: A staging, then 2x32KB B dbuf
  __shared__ __align__(16) float2 sl_s[1024];            // 8KB (sq,label) for this col split
  __shared__ int lab_s[128];

  const int t = threadIdx.x;   // 0..511
  const int lane = t & 63;
  const int w = t >> 6;        // 0..7
  const int wr = w >> 1;       // 0..3 (row quarter)
  const int wc = w & 1;        // 0..1 (col half of 64)
  const int c_l = lane & 15;
  const int kq_l = lane >> 4;
  const int rows0 = blockIdx.x * 128;
  const int cbase = blockIdx.y * (Nn / NSPLIT);

  // ---- stage A (both K halves) into Us; stage sl_s + labels ----
  stage_a(xb, rows0, 0, Us, t);
  stage_a(xb, rows0, 1, Us + 2048 * 8, t);
  sl_s[t] = sqlab[cbase + t];
  sl_s[512 + t] = sqlab[cbase + 512 + t];
  if (t < 128) lab_s[t] = __float_as_int(sqlab[rows0 + t].y);
  __syncthreads();  // A staged (implicit vmcnt(0))

  // ---- A fragments -> registers (forced residency: Us gets overwritten by B dbuf) ----
  const short8* Uv = (const short8*)Us;
  short8 af[16];
#pragma unroll
  for (int k2 = 0; k2 < 8; ++k2)
#pragma unroll
    for (int m = 0; m < 2; ++m) {
      const int kqf = k2 * 4 + kq_l;               // global k-octet 0..31
      const int rl = wr * 32 + m * 16 + c_l;       // local row 0..127
      af[k2 * 2 + m] = Uv[(kqf >> 4) * 2048 + rl * 16 + ((kqf & 15) ^ (rl & 15))];
    }
  int labp[4];
#pragma unroll
  for (int m = 0; m < 2; ++m)
#pragma unroll
    for (int pp = 0; pp < 2; ++pp) {
      const int r0 = wr * 32 + m * 16 + kq_l * 4 + 2 * pp;
      labp[m * 2 + pp] = (lab_s[r0] & 0xffff) | (lab_s[r0 + 1] << 16);
    }
  __syncthreads();  // af/lab reads done before B dbuf overwrites Us

  unsigned short* const Bs0 = Us;               // 32KB (half0 at +0, half1 at +16KB)
  unsigned short* const Bs1 = Us + 2048 * 8;    // 32KB

  // prologue: tile 0 (both halves) -> Bs0
  stage_b(xb, cbase, 0, Bs0, t);
  stage_b(xb, cbase, 1, Bs0 + 1024 * 8, t);

  const int cc0 = wc * 32 + c_l;        // local col (cc&15 == c_l)
  const int cc1 = wc * 32 + 16 + c_l;
  float pmax[8], nmin[8];
#pragma unroll
  for (int i = 0; i < 8; ++i) { pmax[i] = -INFINITY; nmin[i] = INFINITY; }

#pragma unroll 1
  for (int ct2 = 0; ct2 < 8; ++ct2) {
#pragma unroll
    for (int half = 0; half < 2; ++half) {       // static ping-pong: bases are literals
      const int ct = 2 * ct2 + half;
      const unsigned short* const bufR = half ? Bs1 : Bs0;
      unsigned short* const bufW = half ? Bs0 : Bs1;

      __syncthreads();  // bufR's loads (issued one full tile ago) drained; bufW reads done
      if (ct < 15) {
        stage_b(xb, cbase + (ct + 1) * 64, 0, bufW, t);
        stage_b(xb, cbase + (ct + 1) * 64, 1, bufW + 1024 * 8, t);
      }

      f32x4 acc[2][2];
#pragma unroll
      for (int m = 0; m < 2; ++m)
#pragma unroll
        for (int n = 0; n < 2; ++n) acc[m][n] = (f32x4){0.f, 0.f, 0.f, 0.f};

      const short8* const Bv0 = (const short8*)bufR;
      const short8* const Bv1 = (const short8*)(bufR + 1024 * 8);
#pragma unroll
      for (int ks = 0; ks < 8; ++ks) {           // B frags at point of use
        const short8* const B = (ks < 4) ? Bv0 : Bv1;
        const int o = (ks & 3) * 4 + kq_l;
        const short8 bf0 = B[cc0 * 16 + (o ^ c_l)];
        const short8 bf1 = B[cc1 * 16 + (o ^ c_l)];
#pragma unroll
        for (int m = 0; m < 2; ++m) {
          acc[m][0] = __builtin_amdgcn_mfma_f32_16x16x32_bf16(af[ks * 2 + m], bf0, acc[m][0], 0, 0, 0);
          acc[m][1] = __builtin_amdgcn_mfma_f32_16x16x32_bf16(af[ks * 2 + m], bf1, acc[m][1], 0, 0, 0);
        }
      }

      // ---- epilogue: masked running max/min, max3-friendly form ----
      const float2 sl0 = sl_s[ct * 64 + cc0];
      const float2 sl1 = sl_s[ct * 64 + cc1];
      const int lc0 = __float_as_int(sl0.y);
      const int lc1 = __float_as_int(sl1.y);
#pragma unroll
      for (int idx = 0; idx < 8; ++idx) {
        const int m = idx >> 2, q = idx & 3;
        const int lr = (labp[idx >> 1] >> ((idx & 1) * 16)) & 0xffff;
        const float g0 = fmaf(-2.0f, acc[m][0][q], sl0.x);
        const float g1 = fmaf(-2.0f, acc[m][1][q], sl1.x);
        const bool s0 = (lr == lc0), s1 = (lr == lc1);
        const float gp0 = s0 ? g0 : -INFINITY, gp1 = s1 ? g1 : -INFINITY;
        const float gn0 = s0 ? INFINITY : g0,  gn1 = s1 ? INFINITY : g1;
        pmax[idx] = fmaxf(fmaxf(pmax[idx], gp0), gp1);  // -> v_max3_f32
        nmin[idx] = fminf(fminf(nmin[idx], gn0), gn1);  // -> v_min3_f32
      }
    }
  }

  // ---- reduce over 16 col-lanes, 2 atomics per row ----
#pragma unroll
  for (int i = 0; i < 8; ++i) {
    float p = pmax[i], nn2 = nmin[i];
#pragma unroll
    for (int off = 1; off < 16; off <<= 1) {
      p = fmaxf(p, __shfl_xor(p, off));
      nn2 = fminf(nn2, __shfl_xor(nn2, off));
    }
    if (c_l == 0) {
      const int rowg = rows0 + wr * 32 + (i >> 2) * 16 + kq_l * 4 + (i & 3);
      atomicMax(&pos2[rowg], enc_ord(p));
      atomicMin(&neg2[rowg], enc_ord(nn2));
    }
  }
}

// ---------------- K2a: hv + global extremes (parallel) ----------------
__global__ __launch_bounds__(512) void finalize_a_kernel(const float2* __restrict__ sqlab,
                                                         const unsigned int* __restrict__ pos2,
                                                         const unsigned int* __restrict__ neg2,
                                                         float* __restrict__ hv_g,
                                                         unsigned int* __restrict__ gmm) {
  const int i = blockIdx.x * 512 + threadIdx.x;
  const int lane = threadIdx.x & 63;
  const float s = sqlab[i].x;
  const float p2 = fmaxf(s + dec_ord(pos2[i]), 1e-12f);
  const float n2 = fmaxf(s + dec_ord(neg2[i]), 1e-12f);
  const float hv = sqrtf(p2) - sqrtf(n2);
  hv_g[i] = hv;
  float lmax = hv, lmin = hv;
#pragma unroll
  for (int off = 32; off >= 1; off >>= 1) {
    lmax = fmaxf(lmax, __shfl_xor(lmax, off));
    lmin = fminf(lmin, __shfl_xor(lmin, off));
  }
  if (lane == 0) {
    atomicMax(&gmm[0], enc_ord(lmax));
    atomicMin(&gmm[1], enc_ord(lmin));
  }
}

// ---------------- K2b: per-block histogram + per-bin hv sums; last block does cdf+loss ----------------
__global__ __launch_bounds__(512) void finalize_b_kernel(const float* __restrict__ hv_g,
                                                         const unsigned int* __restrict__ gmm,
                                                         float* __restrict__ ghist,
                                                         float* __restrict__ ghsum,
                                                         unsigned int* __restrict__ cnt,
                                                         float* __restrict__ out) {
  __shared__ float hist_s[NBINS];
  __shared__ float hsum_s[NBINS];
  __shared__ unsigned int s_last;
  const int t = threadIdx.x;
  if (t < NBINS) { hist_s[t] = 0.0f; hsum_s[t] = 0.0f; }
  const float maxv = fmaxf(dec_ord(gmm[0]), 2.0f);
  const float minv = fminf(dec_ord(gmm[1]), -2.0f);
  const float bw = (maxv - minv) / (float)(NBINS - 1);
  __syncthreads();

  const int i = blockIdx.x * 512 + t;
  const float hv = hv_g[i];
  int lo = (int)floorf((hv - minv) / bw);
  lo = min(max(lo, 0), NBINS - 1);
  const int hi = min(lo + 1, NBINS - 1);
  const float alpha = 1.0f - (hv - minv - (float)lo * bw) / bw;
  atomicAdd(&hist_s[lo], alpha);
  atomicAdd(&hist_s[hi], 1.0f - alpha);
  atomicAdd(&hsum_s[lo], hv);  // weight uses bin_idx = lo (same floor+clip)
  __syncthreads();

  if (t < NBINS) {
    atomicAdd(&ghist[t], hist_s[t]);
    atomicAdd(&ghsum[t], hsum_s[t]);
  }
  __threadfence();
  if (t == 0) s_last = atomicAdd(cnt, 1u);
  __syncthreads();
  if (s_last != (unsigned int)(gridDim.x - 1)) return;

  // last block: cdf + loss on one wave
  if (t < NBINS) {
    const float h = __hip_atomic_load(&ghist[t], __ATOMIC_RELAXED, __HIP_MEMORY_SCOPE_AGENT);
    const float hs = __hip_atomic_load(&ghsum[t], __ATOMIC_RELAXED, __HIP_MEMORY_SCOPE_AGENT);
    float total = h;
#pragma unroll
    for (int off = 32; off >= 1; off >>= 1) total += __shfl_xor(total, off);
    const float hn = h / (total + 1e-6f);
    float s2 = hn;
#pragma unroll
    for (int off = 32; off >= 1; off >>= 1) s2 += __shfl_xor(s2, off);
    const float pdf = hn / s2;
    float c = pdf;
#pragma unroll
    for (int off = 1; off < 64; off <<= 1) {
      const float u = __shfl_up(c, off);
      if (t >= off) c += u;
    }
    float acc = c * hs;
#pragma unroll
    for (int off = 32; off >= 1; off >>= 1) acc += __shfl_xor(acc, off);
    if (t == 0) out[0] = acc / (float)Nn;
  }
}

// ---------------- launch ----------------
extern "C" void kernel_launch(void* const* d_in, const int* in_sizes, int n_in,
                              void* d_out, int out_size, void* d_ws, size_t ws_size,
                              hipStream_t stream) {
  const float* x = (const float*)d_in[0];
  const int* targets = (const int*)d_in[1];
  float* out = (float*)d_out;

  char* p = (char*)d_ws;
  unsigned short* xb = (unsigned short*)p;  p += (size_t)Nn * Dd * 2;  // 4MB
  float2* sqlab = (float2*)p;               p += (size_t)Nn * 8;
  unsigned int* pos2 = (unsigned int*)p;    p += (size_t)Nn * 4;
  unsigned int* neg2 = (unsigned int*)p;    p += (size_t)Nn * 4;
  float* hv_g = (float*)p;                  p += (size_t)Nn * 4;
  unsigned int* gmm = (unsigned int*)p;     p += 64;
  float* ghist = (float*)p;                 p += NBINS * 4;
  float* ghsum = (float*)p;                 p += NBINS * 4;
  unsigned int* cnt = (unsigned int*)p;

  prep_kernel<<<Nn / 4, 256, 0, stream>>>(x, targets, xb, sqlab, pos2, neg2, gmm, ghist, ghsum, cnt);
  pairwise_kernel<<<dim3(Nn / 128, NSPLIT), 512, 0, stream>>>(xb, sqlab, pos2, neg2);
  finalize_a_kernel<<<Nn / 512, 512, 0, stream>>>(sqlab, pos2, neg2, hv_g, gmm);
  finalize_b_kernel<<<Nn / 512, 512, 0, stream>>>(hv_g, gmm, ghist, ghsum, cnt, out);
}

// Round 17
// 62.303 us; speedup vs baseline: 1.0604x; 1.0604x over previous
//
#include <hip/hip_runtime.h>
#include <math.h>

#define Nn 8192
#define Dd 256
#define NBINS 64
#define NSPLIT 8

typedef __attribute__((ext_vector_type(8))) short short8;
typedef __attribute__((ext_vector_type(4))) float f32x4;

#define GLOAD16(g, l)                                                        \
  __builtin_amdgcn_global_load_lds(                                          \
      (const __attribute__((address_space(1))) void*)(g),                    \
      (__attribute__((address_space(3))) void*)(l), 16, 0, 0)

static __device__ __forceinline__ unsigned short f2bf(float f) {
  unsigned int u = __float_as_uint(f);
  u = (u + 0x7fffu + ((u >> 16) & 1u)) >> 16;  // RNE
  return (unsigned short)u;
}
// order-preserving bijection float -> uint (atomicMax/Min on uint handles negatives)
static __device__ __forceinline__ unsigned int enc_ord(float f) {
  unsigned int u = __float_as_uint(f);
  return (u & 0x80000000u) ? ~u : (u | 0x80000000u);
}
static __device__ __forceinline__ float dec_ord(unsigned int u) {
  unsigned int b2 = (u & 0x80000000u) ? (u ^ 0x80000000u) : ~u;
  return __uint_as_float(b2);
}

// ---------------- K0: bf16 cast + fused (norm,label) + init accumulators ----------------
__global__ __launch_bounds__(256) void prep_kernel(const float* __restrict__ x,
                                                   const int* __restrict__ lab,
                                                   unsigned short* __restrict__ xb,
                                                   float2* __restrict__ sqlab,
                                                   unsigned int* __restrict__ pos2,
                                                   unsigned int* __restrict__ neg2,
                                                   unsigned int* __restrict__ gmm,
                                                   float* __restrict__ ghist,
                                                   float* __restrict__ ghsum,
                                                   unsigned int* __restrict__ cnt) {
  const int w = threadIdx.x >> 6;
  const int lane = threadIdx.x & 63;
  const int row = blockIdx.x * 4 + w;
  const float4 v = *(const float4*)(x + (size_t)row * Dd + lane * 4);
  ushort4 b;
  b.x = f2bf(v.x); b.y = f2bf(v.y); b.z = f2bf(v.z); b.w = f2bf(v.w);
  *(ushort4*)(xb + (size_t)row * Dd + lane * 4) = b;
  float s = v.x * v.x + v.y * v.y + v.z * v.z + v.w * v.w;
#pragma unroll
  for (int off = 32; off >= 1; off >>= 1) s += __shfl_xor(s, off);
  if (lane == 0) {
    sqlab[row] = make_float2(s, __int_as_float(lab[row]));
    pos2[row] = 0x007fffffu;  // enc_ord(-inf)
    neg2[row] = 0xff800000u;  // enc_ord(+inf)
  }
  if (blockIdx.x == 0 && threadIdx.x < NBINS) {
    ghist[threadIdx.x] = 0.0f;
    ghsum[threadIdx.x] = 0.0f;
    if (threadIdx.x == 0) { gmm[0] = 0x007fffffu; gmm[1] = 0xff800000u; cnt[0] = 0u; }
  }
}

// stage one A half-K tile (128 rows x 128 k = 32KB), XOR chunk placement, 256 threads
static __device__ __forceinline__ void stage_a(const unsigned short* __restrict__ xb,
                                               int r0, int hh, unsigned short* buf, int t) {
#pragma unroll
  for (int i = 0; i < 8; ++i) {
    const int c = i * 256 + t;          // 0..2047
    const int col = c >> 4;             // 0..127
    const int kq = (c & 15) ^ (col & 15);
    GLOAD16(xb + (size_t)(r0 + col) * Dd + hh * 128 + kq * 8, buf + (size_t)c * 8);
  }
}
// stage one B half-K tile (64 cols x 128 k = 16KB), 4 global_load_lds per thread
static __device__ __forceinline__ void stage_b(const unsigned short* __restrict__ xb,
                                               int c0, int hh, unsigned short* buf, int t) {
#pragma unroll
  for (int i = 0; i < 4; ++i) {
    const int c = i * 256 + t;          // 0..1023
    const int col = c >> 4;             // 0..63
    const int kq = (c & 15) ^ (col & 15);
    GLOAD16(xb + (size_t)(c0 + col) * Dd + hh * 128 + kq * 8, buf + (size_t)c * 8);
  }
}

// ---------------- K1: MFMA Gram + fused masked max/min ----------------
// r15 base (1 barrier/tile, full-tile dbuf, static ping-pong, no live-across-MFMA prefetch
// regs), with the per-tile compute SPLIT INTO TWO COLUMN PASSES: pass-0 fills acc[:][0],
// pass-1 fills acc[:][1], then epi(n0) -- which depends ONLY on pass-0 -- can issue its
// VALU while the matrix pipe drains pass-1's MFMAs. Only epi(n1) still serializes.
__global__ __launch_bounds__(256, 2) void pairwise_kernel(const unsigned short* __restrict__ xb,
                                                          const float2* __restrict__ sqlab,
                                                          unsigned int* __restrict__ pos2,
                                                          unsigned int* __restrict__ neg2) {
  __shared__ __align__(16) unsigned short Us[4096 * 8];  // 64KB: A staging, then 2x32KB B dbuf
  __shared__ __align__(16) float2 sl_s[1024];            // 8KB (sq,label) for this col split
  __shared__ int lab_s[128];

  const int t = threadIdx.x;   // 0..255
  const int lane = t & 63;
  const int w = t >> 6;        // 0..3
  const int wr = w >> 1;       // 0..1 (row half)
  const int wc = w & 1;        // 0..1 (col half of 64)
  const int c_l = lane & 15;
  const int kq_l = lane >> 4;
  const int rows0 = blockIdx.x * 128;
  const int cbase = blockIdx.y * (Nn / NSPLIT);

  // ---- stage A (both K halves) into Us; stage sl_s + labels ----
  stage_a(xb, rows0, 0, Us, t);
  stage_a(xb, rows0, 1, Us + 2048 * 8, t);
#pragma unroll
  for (int i = 0; i < 4; ++i) sl_s[i * 256 + t] = sqlab[cbase + i * 256 + t];
  if (t < 128) lab_s[t] = __float_as_int(sqlab[rows0 + t].y);
  __syncthreads();  // A staged (implicit vmcnt(0))

  // ---- A fragments -> registers (forced residency: Us gets overwritten by B dbuf) ----
  const short8* Uv = (const short8*)Us;
  short8 af[32];
#pragma unroll
  for (int k2 = 0; k2 < 8; ++k2)
#pragma unroll
    for (int m = 0; m < 4; ++m) {
      const int kqf = k2 * 4 + kq_l;               // global k-octet 0..31
      const int rl = wr * 64 + m * 16 + c_l;       // local row 0..127
      af[k2 * 4 + m] = Uv[(kqf >> 4) * 2048 + rl * 16 + ((kqf & 15) ^ (rl & 15))];
    }
  int labp[8];
#pragma unroll
  for (int m = 0; m < 4; ++m)
#pragma unroll
    for (int pp = 0; pp < 2; ++pp) {
      const int r0 = wr * 64 + m * 16 + kq_l * 4 + 2 * pp;
      labp[m * 2 + pp] = (lab_s[r0] & 0xffff) | (lab_s[r0 + 1] << 16);
    }
  __syncthreads();  // af/lab reads done before B dbuf overwrites Us

  unsigned short* const Bs0 = Us;               // 32KB (half0 at +0, half1 at +16KB)
  unsigned short* const Bs1 = Us + 2048 * 8;    // 32KB

  // prologue: tile 0 (both halves) -> Bs0
  stage_b(xb, cbase, 0, Bs0, t);
  stage_b(xb, cbase, 1, Bs0 + 1024 * 8, t);

  const int cc0 = wc * 32 + c_l;        // local col
  const int cc1 = wc * 32 + 16 + c_l;
  const int x0 = cc0 & 15, x1 = cc1 & 15;
  float pmax[16], nmin[16];
#pragma unroll
  for (int i = 0; i < 16; ++i) { pmax[i] = -INFINITY; nmin[i] = INFINITY; }

#pragma unroll 1
  for (int ct2 = 0; ct2 < 8; ++ct2) {
#pragma unroll
    for (int half = 0; half < 2; ++half) {       // static ping-pong: bases are literals
      const int ct = 2 * ct2 + half;
      const unsigned short* const bufR = half ? Bs1 : Bs0;
      unsigned short* const bufW = half ? Bs0 : Bs1;

      __syncthreads();  // bufR's 8 loads (issued one full tile ago) drained; bufW reads done
      if (ct < 15) {
        stage_b(xb, cbase + (ct + 1) * 64, 0, bufW, t);
        stage_b(xb, cbase + (ct + 1) * 64, 1, bufW + 1024 * 8, t);
      }

      f32x4 acc[4][2];
#pragma unroll
      for (int m = 0; m < 4; ++m)
#pragma unroll
        for (int n = 0; n < 2; ++n) acc[m][n] = (f32x4){0.f, 0.f, 0.f, 0.f};

      const short8* const Bv0 = (const short8*)bufR;
      const short8* const Bv1 = (const short8*)(bufR + 1024 * 8);

      // ---- pass 0: column fragment n=0 (8 ks, 32 MFMA into acc[:][0]) ----
#pragma unroll
      for (int ks = 0; ks < 8; ++ks) {
        const short8* const B = (ks < 4) ? Bv0 : Bv1;
        const int o = (ks & 3) * 4 + kq_l;
        const short8 bf0 = B[cc0 * 16 + (o ^ x0)];
#pragma unroll
        for (int m = 0; m < 4; ++m)
          acc[m][0] = __builtin_amdgcn_mfma_f32_16x16x32_bf16(af[ks * 4 + m], bf0, acc[m][0], 0, 0, 0);
      }
      // ---- pass 1: column fragment n=1 ----
#pragma unroll
      for (int ks = 0; ks < 8; ++ks) {
        const short8* const B = (ks < 4) ? Bv0 : Bv1;
        const int o = (ks & 3) * 4 + kq_l;
        const short8 bf1 = B[cc1 * 16 + (o ^ x1)];
#pragma unroll
        for (int m = 0; m < 4; ++m)
          acc[m][1] = __builtin_amdgcn_mfma_f32_16x16x32_bf16(af[ks * 4 + m], bf1, acc[m][1], 0, 0, 0);
      }

      // ---- epi(n0): depends only on pass 0 -> overlaps pass-1's matrix-pipe drain ----
      const float2 sl0 = sl_s[ct * 64 + cc0];
      const int lc0 = __float_as_int(sl0.y);
#pragma unroll
      for (int idx = 0; idx < 16; ++idx) {
        const int m = idx >> 2, q = idx & 3;
        const int lr = (labp[idx >> 1] >> ((idx & 1) * 16)) & 0xffff;
        const float g0 = fmaf(-2.0f, acc[m][0][q], sl0.x);
        const bool s0 = (lr == lc0);
        pmax[idx] = fmaxf(pmax[idx], s0 ? g0 : -INFINITY);
        nmin[idx] = fminf(nmin[idx], s0 ? INFINITY : g0);
      }
      // ---- epi(n1): serializes after pass 1 ----
      const float2 sl1 = sl_s[ct * 64 + cc1];
      const int lc1 = __float_as_int(sl1.y);
#pragma unroll
      for (int idx = 0; idx < 16; ++idx) {
        const int m = idx >> 2, q = idx & 3;
        const int lr = (labp[idx >> 1] >> ((idx & 1) * 16)) & 0xffff;
        const float g1 = fmaf(-2.0f, acc[m][1][q], sl1.x);
        const bool s1 = (lr == lc1);
        pmax[idx] = fmaxf(pmax[idx], s1 ? g1 : -INFINITY);
        nmin[idx] = fminf(nmin[idx], s1 ? INFINITY : g1);
      }
    }
  }

  // ---- reduce over 16 col-lanes, 2 atomics per row ----
#pragma unroll
  for (int i = 0; i < 16; ++i) {
    float p = pmax[i], nn2 = nmin[i];
#pragma unroll
    for (int off = 1; off < 16; off <<= 1) {
      p = fmaxf(p, __shfl_xor(p, off));
      nn2 = fminf(nn2, __shfl_xor(nn2, off));
    }
    if (c_l == 0) {
      const int rowg = rows0 + wr * 64 + (i >> 2) * 16 + kq_l * 4 + (i & 3);
      atomicMax(&pos2[rowg], enc_ord(p));
      atomicMin(&neg2[rowg], enc_ord(nn2));
    }
  }
}

// ---------------- K2a: hv + global extremes (parallel) ----------------
__global__ __launch_bounds__(512) void finalize_a_kernel(const float2* __restrict__ sqlab,
                                                         const unsigned int* __restrict__ pos2,
                                                         const unsigned int* __restrict__ neg2,
                                                         float* __restrict__ hv_g,
                                                         unsigned int* __restrict__ gmm) {
  const int i = blockIdx.x * 512 + threadIdx.x;
  const int lane = threadIdx.x & 63;
  const float s = sqlab[i].x;
  const float p2 = fmaxf(s + dec_ord(pos2[i]), 1e-12f);
  const float n2 = fmaxf(s + dec_ord(neg2[i]), 1e-12f);
  const float hv = sqrtf(p2) - sqrtf(n2);
  hv_g[i] = hv;
  float lmax = hv, lmin = hv;
#pragma unroll
  for (int off = 32; off >= 1; off >>= 1) {
    lmax = fmaxf(lmax, __shfl_xor(lmax, off));
    lmin = fminf(lmin, __shfl_xor(lmin, off));
  }
  if (lane == 0) {
    atomicMax(&gmm[0], enc_ord(lmax));
    atomicMin(&gmm[1], enc_ord(lmin));
  }
}

// ---------------- K2b: per-block histogram + per-bin hv sums; last block does cdf+loss ----------------
__global__ __launch_bounds__(512) void finalize_b_kernel(const float* __restrict__ hv_g,
                                                         const unsigned int* __restrict__ gmm,
                                                         float* __restrict__ ghist,
                                                         float* __restrict__ ghsum,
                                                         unsigned int* __restrict__ cnt,
                                                         float* __restrict__ out) {
  __shared__ float hist_s[NBINS];
  __shared__ float hsum_s[NBINS];
  __shared__ unsigned int s_last;
  const int t = threadIdx.x;
  if (t < NBINS) { hist_s[t] = 0.0f; hsum_s[t] = 0.0f; }
  const float maxv = fmaxf(dec_ord(gmm[0]), 2.0f);
  const float minv = fminf(dec_ord(gmm[1]), -2.0f);
  const float bw = (maxv - minv) / (float)(NBINS - 1);
  __syncthreads();

  const int i = blockIdx.x * 512 + t;
  const float hv = hv_g[i];
  int lo = (int)floorf((hv - minv) / bw);
  lo = min(max(lo, 0), NBINS - 1);
  const int hi = min(lo + 1, NBINS - 1);
  const float alpha = 1.0f - (hv - minv - (float)lo * bw) / bw;
  atomicAdd(&hist_s[lo], alpha);
  atomicAdd(&hist_s[hi], 1.0f - alpha);
  atomicAdd(&hsum_s[lo], hv);  // weight uses bin_idx = lo (same floor+clip)
  __syncthreads();

  if (t < NBINS) {
    atomicAdd(&ghist[t], hist_s[t]);
    atomicAdd(&ghsum[t], hsum_s[t]);
  }
  __threadfence();
  if (t == 0) s_last = atomicAdd(cnt, 1u);
  __syncthreads();
  if (s_last != (unsigned int)(gridDim.x - 1)) return;

  // last block: cdf + loss on one wave
  if (t < NBINS) {
    const float h = __hip_atomic_load(&ghist[t], __ATOMIC_RELAXED, __HIP_MEMORY_SCOPE_AGENT);
    const float hs = __hip_atomic_load(&ghsum[t], __ATOMIC_RELAXED, __HIP_MEMORY_SCOPE_AGENT);
    float total = h;
#pragma unroll
    for (int off = 32; off >= 1; off >>= 1) total += __shfl_xor(total, off);
    const float hn = h / (total + 1e-6f);
    float s2 = hn;
#pragma unroll
    for (int off = 32; off >= 1; off >>= 1) s2 += __shfl_xor(s2, off);
    const float pdf = hn / s2;
    float c = pdf;
#pragma unroll
    for (int off = 1; off < 64; off <<= 1) {
      const float u = __shfl_up(c, off);
      if (t >= off) c += u;
    }
    float acc = c * hs;
#pragma unroll
    for (int off = 32; off >= 1; off >>= 1) acc += __shfl_xor(acc, off);
    if (t == 0) out[0] = acc / (float)Nn;
  }
}

// ---------------- launch ----------------
extern "C" void kernel_launch(void* const* d_in, const int* in_sizes, int n_in,
                              void* d_out, int out_size, void* d_ws, size_t ws_size,
                              hipStream_t stream) {
  const float* x = (const float*)d_in[0];
  const int* targets = (const int*)d_in[1];
  float* out = (float*)d_out;

  char* p = (char*)d_ws;
  unsigned short* xb = (unsigned short*)p;  p += (size_t)Nn * Dd * 2;  // 4MB
  float2* sqlab = (float2*)p;               p += (size_t)Nn * 8;
  unsigned int* pos2 = (unsigned int*)p;    p += (size_t)Nn * 4;
  unsigned int* neg2 = (unsigned int*)p;    p += (size_t)Nn * 4;
  float* hv_g = (float*)p;                  p += (size_t)Nn * 4;
  unsigned int* gmm = (unsigned int*)p;     p += 64;
  float* ghist = (float*)p;                 p += NBINS * 4;
  float* ghsum = (float*)p;                 p += NBINS * 4;
  unsigned int* cnt = (unsigned int*)p;

  prep_kernel<<<Nn / 4, 256, 0, stream>>>(x, targets, xb, sqlab, pos2, neg2, gmm, ghist, ghsum, cnt);
  pairwise_kernel<<<dim3(Nn / 128, NSPLIT), 256, 0, stream>>>(xb, sqlab, pos2, neg2);
  finalize_a_kernel<<<Nn / 512, 512, 0, stream>>>(sqlab, pos2, neg2, hv_g, gmm);
  finalize_b_kernel<<<Nn / 512, 512, 0, stream>>>(hv_g, gmm, ghist, ghsum, cnt, out);
}